// Round 16
// baseline (66.442 us; speedup 1.0000x reference)
//
#include <hip/hip_runtime.h>
#include <hip/hip_bf16.h>

// ---------------------------------------------------------------------------
// Diagonal-covariance GMM log-likelihoods as one bf16 MFMA GEMM + bias:
//   out[m,k] = sum_f [ x^2 * (-0.5/cov) + x * (mu/cov) ] + bias[k]
// GEMM: M=16384, N=512 (padded from 500), K2=2048 (interleaved x^2/x pairs)
//
// R15: occupancy by N-split. R10 (best tie) was capped at 2 blocks/CU purely
// by grid size (512). R14 showed more waves help is possible but duplicated B
// 4x (FETCH 41->64MB). Here: BM=128 x BN=64 -> 1024 blocks = 4 blocks/CU =
// 4 waves/SIMD, with X-panel geometry IDENTICAL to R10 (BM=64 thrice failed;
// n-siblings 128 apart in bid -> same XCD) and B duplicated only 2x (L1).
//  - per-wave: acc[4][2]=32 AGPR, B single set 16 VGPR (refill-after-consume),
//    A 16 VGPR -> ~100 regs -> 4 waves/SIMD by regs too. (256,2), no clamp.
//  - structure = R10: fragment-major B image (retiled for BN=64), A XOR-
//    swizzled LDS dbuf (2x16KB), one lgkm-only barrier/iter, setprio on MFMA.
// ---------------------------------------------------------------------------

typedef __attribute__((ext_vector_type(8))) __bf16 bf16x8;
typedef __attribute__((ext_vector_type(4))) float  f32x4;

#define LOG_2PI 1.837877066409345339082f

constexpr int M_TOT = 16384;   // B*T
constexpr int F_DIM = 1024;
constexpr int K_GMM = 500;
constexpr int N_PAD = 512;

constexpr int BM  = 128;
constexpr int BN  = 64;
constexpr int BKF = 32;              // K-step in floats (=> 64 bf16 along K2)
constexpr int NIT = F_DIM / BKF;     // 32 K-steps

// pack (bf16(x*x), bf16(x)) into one dword: low16 = x^2 (even K2 slot), hi16 = x
__device__ __forceinline__ unsigned pack_sq_x(float x) {
    __hip_bfloat162 h = __float22bfloat162_rn(make_float2(x * x, x));
    union { __hip_bfloat162 h; unsigned u; } cv;
    cv.h = h;
    return cv.u;
}

// ---------------------------------------------------------------------------
// prep: FRAGMENT-MAJOR W image retiled for BN=64 (8 n-tiles) + fp32 bias.
// Row k (0..511): tt=k>>6 (n_tile), b=(k>>4)&3 (16-col group), lo=k&15.
// Row dword d (0..1023): it=d>>5, c=(d>>4)&1, hi=(d>>2)&3, jj=d&3.
// Image dword addr = ((tt*32+it)*8 + (b*2+c))*256 + (hi*16+lo)*4 + jj.
// => per (tt,it,frag) a contiguous 1KB block in exact lane order.
// Value: (bf16(-0.5/cov), bf16(mu/cov)); rows k>=500 zeroed, bias=0 there.
// ---------------------------------------------------------------------------
__global__ __launch_bounds__(256) void prep_w_kernel(
    const float* __restrict__ mu, const float* __restrict__ cov,
    unsigned* __restrict__ Wimg, float* __restrict__ bias)
{
    const int k = blockIdx.x;           // 0..511 (component row)
    const int t = threadIdx.x;
    const int tt = k >> 6;
    const int b  = (k >> 4) & 3;
    const int lo = k & 15;
    float sl = 0.f, sq = 0.f;
    #pragma unroll
    for (int j = 0; j < 4; ++j) {
        const int d  = t + j * 256;          // row dword index 0..1023
        const int it = d >> 5;
        const int c  = (d >> 4) & 1;
        const int hi = (d >> 2) & 3;
        const int jj = d & 3;
        const int dw = ((tt * 32 + it) * 8 + (b * 2 + c)) * 256
                     + (hi * 16 + lo) * 4 + jj;
        if (k < K_GMM) {
            const float cv_ = cov[k * F_DIM + d];
            const float m_  = mu[k * F_DIM + d];
            const float ic  = 1.0f / cv_;
            __hip_bfloat162 h = __float22bfloat162_rn(make_float2(-0.5f * ic, m_ * ic));
            union { __hip_bfloat162 h; unsigned u; } cvt; cvt.h = h;
            Wimg[dw] = cvt.u;
            sl += logf(cv_);
            sq += m_ * m_ * ic;
        } else {
            Wimg[dw] = 0u;
        }
    }
    #pragma unroll
    for (int off = 32; off > 0; off >>= 1) {
        sl += __shfl_down(sl, off, 64);
        sq += __shfl_down(sq, off, 64);
    }
    __shared__ float red[8];
    if ((t & 63) == 0) { red[(t >> 6) * 2] = sl; red[(t >> 6) * 2 + 1] = sq; }
    __syncthreads();
    if (t == 0) {
        const float SL = red[0] + red[2] + red[4] + red[6];
        const float SQ = red[1] + red[3] + red[5] + red[7];
        bias[k] = (k < K_GMM)
                ? (-0.5f * (F_DIM * LOG_2PI) - 0.5f * SL - 0.5f * SQ) : 0.f;
    }
}

// ---------------------------------------------------------------------------
// GEMM: 128x64 tile, 4 waves (2 row x 2 col, each 64x32), mfma 16x16x32_bf16.
// LDS 32KB: A dbuf at {0,16K}, XOR-swizzled [128][64] bf16; epilogue overlay.
// B: per-wave 4 contiguous 1KB fragment loads (fragment-major image), single
// set refilled after consumption. One lgkm-only barrier per iteration.
// 1024 blocks (4/CU, 4 waves/SIMD); m=bid&127, n=bid>>7 -> n-siblings 128
// apart (same XCD mod 8), X panel = R10's exactly.
// ---------------------------------------------------------------------------
__global__ __launch_bounds__(256, 2) void gemm_kernel(
    const float* __restrict__ X, const unsigned* __restrict__ Wimg,
    const float* __restrict__ bias, float* __restrict__ out)
{
    __shared__ __align__(16) char smem[32768];
    float* ep = reinterpret_cast<float*>(smem);   // 128x64 fp32 epilogue (32KB)

    const int bid    = blockIdx.x;
    const int m_base = (bid & 127) * BM;
    const int n_tile = bid >> 7;                  // 0..7
    const int n_base = n_tile * BN;

    const int tid  = threadIdx.x;
    const int lane = tid & 63;
    const int wv   = tid >> 6;
    const int wr   = (wv >> 1) * 64;    // wave row block (0/64)
    const int wc   = (wv & 1) * 32;     // wave col block (0/32)
    const int wcb  = wc >> 4;           // first 16-col group (0 or 2)
    const int hi   = lane >> 4;         // 0..3
    const int lo   = lane & 15;
    const int lsw  = lo & 7;            // lane-constant fragment read swizzle

    const int sr = tid >> 1;            // A staging row 0..127
    const int sh = tid & 1;             // staging half (chunks 0-3 / 4-7)

    const float4* Xv = reinterpret_cast<const float4*>(X);     // X row = 256 float4
    const bf16x8* Wf = reinterpret_cast<const bf16x8*>(Wimg);
    const int wbase = n_tile * 32 * 8 * 64;                    // bf16x8 units

    f32x4 acc[4][2];
    #pragma unroll
    for (int a = 0; a < 4; ++a)
        #pragma unroll
        for (int b = 0; b < 2; ++b)
            acc[a][b] = (f32x4){0.f, 0.f, 0.f, 0.f};

    auto loadA = [&](int itS, float4* ar) {           // 4 global float4 / thread
        #pragma unroll
        for (int j = 0; j < 4; ++j)
            ar[j] = Xv[(size_t)(m_base + sr) * (F_DIM / 4) + itS * 8 + sh * 4 + j];
    };
    auto packA = [&](const float4* ar, int ab) {      // pack + swizzled ds_write
        unsigned short* Ad = reinterpret_cast<unsigned short*>(smem + ab * 16384);
        #pragma unroll
        for (int j = 0; j < 4; ++j) {
            const int chunk = (sh * 4 + j) ^ (sr & 7);
            uint4 wa;
            wa.x = pack_sq_x(ar[j].x);
            wa.y = pack_sq_x(ar[j].y);
            wa.z = pack_sq_x(ar[j].z);
            wa.w = pack_sq_x(ar[j].w);
            *reinterpret_cast<uint4*>(&Ad[sr * 64 + chunk * 8]) = wa;
        }
    };
    auto loadB = [&](int itS, bf16x8* br) {           // 4 contiguous 1KB wave-loads
        #pragma unroll
        for (int bi = 0; bi < 2; ++bi)
            #pragma unroll
            for (int c = 0; c < 2; ++c)
                br[bi * 2 + c] = Wf[wbase + (itS * 8 + (wcb + bi) * 2 + c) * 64 + lane];
    };
    auto mfmas = [&](int ab, const bf16x8* br) {      // 8 ds_read_b128 + 16 MFMA
        const unsigned short* Asc =
            reinterpret_cast<const unsigned short*>(smem + ab * 16384);
        #pragma unroll
        for (int c = 0; c < 2; ++c) {
            bf16x8 af[4];
            #pragma unroll
            for (int a = 0; a < 4; ++a) {
                const int row   = wr + a * 16 + lo;
                const int chunk = (c * 4 + hi) ^ lsw;
                af[a] = *reinterpret_cast<const bf16x8*>(&Asc[row * 64 + chunk * 8]);
            }
            __builtin_amdgcn_s_setprio(1);
            #pragma unroll
            for (int a = 0; a < 4; ++a)
                #pragma unroll
                for (int b = 0; b < 2; ++b)
                    acc[a][b] = __builtin_amdgcn_mfma_f32_16x16x32_bf16(
                        af[a], br[b * 2 + c], acc[a][b], 0, 0, 0);
            __builtin_amdgcn_s_setprio(0);
        }
    };

    // ---- prologue ----
    float4 aA[4];
    bf16x8 bb[4];
    loadA(0, aA);
    loadB(0, bb);
    packA(aA, 0);          // waits only aA's own loads (reg deps)
    loadA(1, aA);          // A(1) in flight
    asm volatile("s_waitcnt lgkmcnt(0)" ::: "memory");
    __builtin_amdgcn_s_barrier();
    __builtin_amdgcn_sched_barrier(0);

    // ---- main loop: one lgkm-only barrier per iteration ----
    for (int it = 0; it < NIT; ++it) {
        const int ab = it & 1;
        if (it + 1 < NIT) {
            packA(aA, ab ^ 1);                 // A(it+1) -> other buffer
            if (it + 2 < NIT) loadA(it + 2, aA);
        }
        mfmas(ab, bb);
        if (it + 1 < NIT) loadB(it + 1, bb);   // refill after consume
        asm volatile("s_waitcnt lgkmcnt(0)" ::: "memory");
        __builtin_amdgcn_s_barrier();
        __builtin_amdgcn_sched_barrier(0);
    }

    // ---- Epilogue: acc+bias -> 32KB LDS fp32 tile -> dense coalesced rows ----
    // (final loop barrier separates last ds_reads from ep overwrite)
    #pragma unroll
    for (int b = 0; b < 2; ++b) {
        const int col = wc + b * 16 + lo;
        const float bv = bias[n_base + col];
        #pragma unroll
        for (int a = 0; a < 4; ++a) {
            const int er = wr + a * 16 + hi * 4;  // D: col=lane&15, row=(lane>>4)*4+i
            #pragma unroll
            for (int i = 0; i < 4; ++i)
                ep[(er + i) * 64 + col] = acc[a][b][i] + bv;
        }
    }
    __syncthreads();

    const int ncols = (K_GMM - n_base < BN) ? (K_GMM - n_base) : BN;  // 64 or 52
    #pragma unroll
    for (int q = 0; q < 8; ++q) {
        const int f    = q * 256 + tid;   // float4 id in 128x16 grid
        const int row  = f >> 4;
        const int slot = f & 15;
        if (slot * 4 < ncols) {
            const float4 v = *reinterpret_cast<const float4*>(&ep[row * 64 + slot * 4]);
            *reinterpret_cast<float4*>(
                &out[(size_t)(m_base + row) * K_GMM + n_base + slot * 4]) = v;
        }
    }
}

extern "C" void kernel_launch(void* const* d_in, const int* in_sizes, int n_in,
                              void* d_out, int out_size, void* d_ws, size_t ws_size,
                              hipStream_t stream)
{
    (void)in_sizes; (void)n_in; (void)out_size; (void)ws_size;
    const float* X   = (const float*)d_in[0];
    const float* mu  = (const float*)d_in[1];
    const float* cov = (const float*)d_in[2];
    float* out = (float*)d_out;

    // workspace: W image = 512*1024 dwords (2 MiB), then bias[512] f32
    unsigned* Wimg = (unsigned*)d_ws;
    float*    bias = (float*)((char*)d_ws + (size_t)N_PAD * F_DIM * 4);

    prep_w_kernel<<<dim3(N_PAD), dim3(256), 0, stream>>>(mu, cov, Wimg, bias);
    gemm_kernel<<<dim3((M_TOT / BM) * (N_PAD / BN)), dim3(256), 0, stream>>>(X, Wimg, bias, out);
}